// Round 2
// baseline (7412.383 us; speedup 1.0000x reference)
//
#include <hip/hip_runtime.h>
#include <hip/hip_bf16.h>
#include <math.h>

#define NJ 22

// ---------------- LDS layout (floats) ----------------
// R1: 5632  (tok[22][64]@0 + qkv[22][192]@1408) / hid fp32 [22][256]
// R2: 5632  (h / hn fp32 (in place) / out_enc / embed)
// R3: 1408  (attn_out fp32 [22][64])
// S : 256   (x@0 (<=88), mean@96 (22), rstd@118 (22), delta@160 (88))
#define R2_OFF 5632
#define R3_OFF 11264
#define S_OFF  12672
#define LDS_FLOATS 12928
#define S_X 0
#define S_MEAN 96
#define S_RSTD 118
#define S_DELTA 160

struct Args {
    const float *q_t, *skelA, *skelB, *quat_mean, *quat_std;
    const float *qe_tok_W, *qe_tok_b, *qe_qkv_W, *qe_qkv_b, *qe_o_W, *qe_o_b;
    const float *qe_ln_g, *qe_ln_b, *qe_m1_W, *qe_m1_b, *qe_m2_W, *qe_m2_b;
    const float *se_tok_W, *se_tok_b, *se_qkv_W, *se_qkv_b, *se_o_W, *se_o_b;
    const float *se_ln_g, *se_ln_b, *se_m1_W, *se_m1_b, *se_m2_W, *se_m2_b;
    const float *emb_W, *emb_b, *del_W, *del_b;
    const float *P;   // precomputed pe @ emb_W + emb_b  [22][128]
    float *out;
};

// acc[r] += sum_k A[r*LDA+k] * Wcol[k*C], A in LDS fp32 (broadcast reads, float4)
template<int R, int K, int LDA, int C>
__device__ __forceinline__ void gemm_col(float *acc, const float* __restrict__ Wcol,
                                         const float *A) {
#pragma unroll 2
    for (int k = 0; k < K; k += 4) {
        float w0 = Wcol[(k + 0) * C], w1 = Wcol[(k + 1) * C];
        float w2 = Wcol[(k + 2) * C], w3 = Wcol[(k + 3) * C];
#pragma unroll
        for (int r = 0; r < R; r++) {
            float4 a = *(const float4 *)(A + r * LDA + k);
            acc[r] = fmaf(a.x, w0, fmaf(a.y, w1, fmaf(a.z, w2, fmaf(a.w, w3, acc[r]))));
        }
    }
}

// attention over QKV lds tile [22][192] (layout q|k|v each [heads][HD]); out O [22][64]
template<int H, int HD>
__device__ __forceinline__ void attention(const float *QKV, float *O, int t) {
    if (t < H * NJ) {
        int hh = t / NJ, r = t - hh * NJ;
        const float *qp = QKV + r * 192 + hh * HD;
        float q[HD];
#pragma unroll
        for (int d = 0; d < HD; d += 4) {
            float4 v4 = *(const float4 *)(qp + d);
            q[d] = v4.x; q[d + 1] = v4.y; q[d + 2] = v4.z; q[d + 3] = v4.w;
        }
        float s[NJ];
        float mx = -1e30f;
#pragma unroll
        for (int j = 0; j < NJ; j++) {
            const float *kp = QKV + j * 192 + 64 + hh * HD;
            float acc = 0.f;
#pragma unroll
            for (int d = 0; d < HD; d += 4) {
                float4 v4 = *(const float4 *)(kp + d);
                acc += q[d] * v4.x + q[d + 1] * v4.y + q[d + 2] * v4.z + q[d + 3] * v4.w;
            }
            s[j] = acc * 0.125f;            // scale = 64^-0.5 for both encoders
            mx = fmaxf(mx, s[j]);
        }
        float sum = 0.f;
#pragma unroll
        for (int j = 0; j < NJ; j++) { s[j] = expf(s[j] - mx); sum += s[j]; }
        float inv = 1.f / sum;
        float o[HD];
#pragma unroll
        for (int d = 0; d < HD; d++) o[d] = 0.f;
#pragma unroll
        for (int j = 0; j < NJ; j++) {
            float p = s[j] * inv;
            const float *vp = QKV + j * 192 + 128 + hh * HD;
#pragma unroll
            for (int d = 0; d < HD; d += 4) {
                float4 v4 = *(const float4 *)(vp + d);
                o[d] = fmaf(p, v4.x, o[d]);   o[d + 1] = fmaf(p, v4.y, o[d + 1]);
                o[d + 2] = fmaf(p, v4.z, o[d + 2]); o[d + 3] = fmaf(p, v4.w, o[d + 3]);
            }
        }
#pragma unroll
        for (int d = 0; d < HD; d++) O[r * 64 + hh * HD + d] = o[d];
    }
}

template<int CH>
__device__ __forceinline__ void ln_stats(const float *Hm, float *S, int t) {
    int wave = t >> 6, lane = t & 63;
    for (int r = wave; r < NJ; r += 4) {
        float s1 = 0.f, s2 = 0.f;
        for (int c = lane; c < CH; c += 64) {
            float v = Hm[r * CH + c];
            s1 += v; s2 = fmaf(v, v, s2);
        }
#pragma unroll
        for (int off = 32; off > 0; off >>= 1) {
            s1 += __shfl_down(s1, off);
            s2 += __shfl_down(s2, off);
        }
        if (lane == 0) {
            float m = s1 * (1.f / CH);
            float var = s2 * (1.f / CH) - m * m;
            S[S_MEAN + r] = m;
            S[S_RSTD + r] = rsqrtf(var + 1e-5f);
        }
    }
}

// One SkelEncoder pass for one item; accumulates its emb_W slice into embacc regs.
__device__ __forceinline__ void se_encode(const Args &A, const float *X, int embBase,
                                          float *lds, float (&embacc)[NJ], int t) {
    float *R1 = lds, *R2 = lds + R2_OFF, *R3 = lds + R3_OFF, *S = lds + S_OFF;
    if (t < NJ * 3) S[S_X + t] = X[t];
    __syncthreads();
    if (t < 64) {                       // tok: C=64, K=3
        float acc[NJ]; float b = A.se_tok_b[t];
#pragma unroll
        for (int r = 0; r < NJ; r++) acc[r] = b;
#pragma unroll
        for (int k = 0; k < 3; k++) {
            float w = A.se_tok_W[k * 64 + t];
#pragma unroll
            for (int r = 0; r < NJ; r++) acc[r] = fmaf(S[S_X + r * 3 + k], w, acc[r]);
        }
#pragma unroll
        for (int r = 0; r < NJ; r++) R1[r * 64 + t] = acc[r];
    }
    __syncthreads();
    if (t < 192) {                      // qkv: C=192, K=64
        float acc[NJ]; float b = A.se_qkv_b[t];
#pragma unroll
        for (int r = 0; r < NJ; r++) acc[r] = b;
        gemm_col<NJ, 64, 64, 192>(acc, A.se_qkv_W + t, R1);
#pragma unroll
        for (int r = 0; r < NJ; r++) R1[1408 + r * 192 + t] = acc[r];
    }
    __syncthreads();
    attention<2, 32>(R1 + 1408, R3, t);
    __syncthreads();
    float res[NJ];
    if (t < 128) {                      // h = attn_out @ o_W: C=128, K=64
        float b = A.se_o_b[t];
#pragma unroll
        for (int r = 0; r < NJ; r++) res[r] = b;
        gemm_col<NJ, 64, 64, 128>(res, A.se_o_W + t, R3);
#pragma unroll
        for (int r = 0; r < NJ; r++) R2[r * 128 + t] = res[r];
    }
    __syncthreads();
    ln_stats<128>(R2, S, t);
    __syncthreads();
    if (t < 128) {                      // hn (fp32) overwrites h in R2; res keeps h
        float g = A.se_ln_g[t], bb = A.se_ln_b[t];
#pragma unroll
        for (int r = 0; r < NJ; r++)
            R2[r * 128 + t] = (res[r] - S[S_MEAN + r]) * S[S_RSTD + r] * g + bb;
    }
    __syncthreads();
    {                                   // mlp1: C=256, K=128 (all threads)
        float acc[NJ];
#pragma unroll
        for (int r = 0; r < NJ; r++) acc[r] = 0.f;
        gemm_col<NJ, 128, 128, 256>(acc, A.se_m1_W + t, R2);
        float b1 = A.se_m1_b[t];
#pragma unroll
        for (int r = 0; r < NJ; r++) R1[r * 256 + t] = fmaxf(acc[r] + b1, 0.f);
    }
    __syncthreads();
    if (t < 128) {                      // mlp2 + residual: C=128, K=256
        gemm_col<NJ, 256, 256, 128>(res, A.se_m2_W + t, R1);
        float b2 = A.se_m2_b[t];
#pragma unroll
        for (int r = 0; r < NJ; r++) res[r] += b2;
    }
    __syncthreads();                    // all mlp1 reads of R2 (hn) done
    if (t < 128) {
#pragma unroll
        for (int r = 0; r < NJ; r++) R2[r * 128 + t] = res[r];   // out_enc
    }
    __syncthreads();
    if (t < 128)                        // fold into head: embacc += out_enc @ emb_W[slice]
        gemm_col<NJ, 128, 128, 128>(embacc, A.emb_W + embBase * 128 + t, R2);
}

__global__ __launch_bounds__(256) void fused_kernel(Args A) {
    __shared__ __align__(16) float lds[LDS_FLOATS];
    const int item = blockIdx.x;
    const int t = threadIdx.x;
    float *R1 = lds, *R2 = lds + R2_OFF, *R3 = lds + R3_OFF, *S = lds + S_OFF;

    float embacc[NJ];
#pragma unroll
    for (int r = 0; r < NJ; r++) embacc[r] = 0.f;

    // ================= QuatEncoder =================
    if (t < NJ * 4) S[S_X + t] = A.q_t[item * NJ * 4 + t];
    __syncthreads();
    if (t < 64) {                       // tok: C=64, K=4
        float acc[NJ]; float b = A.qe_tok_b[t];
#pragma unroll
        for (int r = 0; r < NJ; r++) acc[r] = b;
#pragma unroll
        for (int k = 0; k < 4; k++) {
            float w = A.qe_tok_W[k * 64 + t];
#pragma unroll
            for (int r = 0; r < NJ; r++) acc[r] = fmaf(S[S_X + r * 4 + k], w, acc[r]);
        }
#pragma unroll
        for (int r = 0; r < NJ; r++) R1[r * 64 + t] = acc[r];
    }
    __syncthreads();
    if (t < 192) {                      // qkv: C=192, K=64
        float acc[NJ]; float b = A.qe_qkv_b[t];
#pragma unroll
        for (int r = 0; r < NJ; r++) acc[r] = b;
        gemm_col<NJ, 64, 64, 192>(acc, A.qe_qkv_W + t, R1);
#pragma unroll
        for (int r = 0; r < NJ; r++) R1[1408 + r * 192 + t] = acc[r];
    }
    __syncthreads();
    attention<4, 16>(R1 + 1408, R3, t);
    __syncthreads();
    float res[NJ];
    {                                   // h = attn_out @ o_W: C=256, K=64 (all threads)
        float b = A.qe_o_b[t];
#pragma unroll
        for (int r = 0; r < NJ; r++) res[r] = b;
        gemm_col<NJ, 64, 64, 256>(res, A.qe_o_W + t, R3);
#pragma unroll
        for (int r = 0; r < NJ; r++) R2[r * 256 + t] = res[r];
    }
    __syncthreads();
    ln_stats<256>(R2, S, t);
    __syncthreads();
    {                                   // hn (fp32) overwrites h in R2; res keeps h
        float g = A.qe_ln_g[t], bb = A.qe_ln_b[t];
#pragma unroll
        for (int r = 0; r < NJ; r++)
            R2[r * 256 + t] = (res[r] - S[S_MEAN + r]) * S[S_RSTD + r] * g + bb;
    }
    __syncthreads();
#pragma unroll 1
    for (int p = 0; p < 2; p++) {       // mlp over hid halves of 512
        {
            float acc[NJ];
#pragma unroll
            for (int r = 0; r < NJ; r++) acc[r] = 0.f;
            gemm_col<NJ, 256, 256, 512>(acc, A.qe_m1_W + p * 256 + t, R2);
            float b1 = A.qe_m1_b[p * 256 + t];
#pragma unroll
            for (int r = 0; r < NJ; r++) R1[r * 256 + t] = fmaxf(acc[r] + b1, 0.f);
        }
        __syncthreads();
        gemm_col<NJ, 256, 256, 256>(res, A.qe_m2_W + p * 256 * 256 + t, R1);
        __syncthreads();
    }
    {
        float b2 = A.qe_m2_b[t];
#pragma unroll
        for (int r = 0; r < NJ; r++) { res[r] += b2; R2[r * 256 + t] = res[r]; }
    }
    __syncthreads();
    if (t < 128)                        // embacc += qe_out @ emb_W[0:256]
        gemm_col<NJ, 256, 256, 128>(embacc, A.emb_W + t, R2);

    // ================= SkelEncoders (shared weights) =================
    se_encode(A, A.skelA + item * NJ * 3, 256, lds, embacc, t);
    se_encode(A, A.skelB + item * NJ * 3, 384, lds, embacc, t);

    // ================= Head =================
    __syncthreads();
    if (t < 128) {
#pragma unroll
        for (int r = 0; r < NJ; r++) {
            float e = fmaf(22.627416997969522f, embacc[r], A.P[r * 128 + t]);
            R2[r * 128 + t] = fmaxf(e, 0.f);
        }
    }
    __syncthreads();
    if (t < NJ * 4) {                   // delta = embed @ del_W + del_b, scale/shift
        int r = t >> 2, d = t & 3;
        float acc = A.del_b[d];
        for (int c = 0; c < 128; c++)
            acc = fmaf(R2[r * 128 + c], A.del_W[c * 4 + d], acc);
        acc = fmaf(acc, A.quat_std[t], A.quat_mean[t]);
        S[S_DELTA + t] = acc;
    }
    __syncthreads();
    if (t < NJ * 4) {                   // normalize quaternion
        int r = t >> 2;
        float x0 = S[S_DELTA + r * 4 + 0], x1 = S[S_DELTA + r * 4 + 1];
        float x2 = S[S_DELTA + r * 4 + 2], x3 = S[S_DELTA + r * 4 + 3];
        float inv = 1.f / sqrtf(x0 * x0 + x1 * x1 + x2 * x2 + x3 * x3);
        A.out[item * NJ * 4 + t] = S[S_DELTA + t] * inv;
    }
}

// Setup: P[r][c] = (pe @ emb_W)[r][c] + emb_b[c]   (pos = cat*sqrt(512) + pe)
// Precise math: runs once over 22*128 outputs, cost negligible.
__global__ void pe_emb_kernel(const float *__restrict__ emb_W,
                              const float *__restrict__ emb_b, float *P) {
    int r = blockIdx.x;        // 0..21
    int c = threadIdx.x;       // 0..127
    float acc = emb_b[c];
    const float k = -2.f * logf(10000.f) / 512.f;
    for (int i = 0; i < 256; i++) {
        float ang = (float)r * expf((float)i * k);
        acc = fmaf(sinf(ang), emb_W[(2 * i) * 128 + c], acc);
        acc = fmaf(cosf(ang), emb_W[(2 * i + 1) * 128 + c], acc);
    }
    P[r * 128 + c] = acc;
}

extern "C" void kernel_launch(void *const *d_in, const int *in_sizes, int n_in,
                              void *d_out, int out_size, void *d_ws, size_t ws_size,
                              hipStream_t stream) {
    Args A;
    const float **p = (const float **)&A;
    for (int i = 0; i < 33; i++) p[i] = (const float *)d_in[i];
    float *P = (float *)d_ws;
    A.P = P;
    A.out = (float *)d_out;
    int n_items = in_sizes[0] / (NJ * 4);

    pe_emb_kernel<<<NJ, 128, 0, stream>>>(A.emb_W, A.emb_b, P);
    fused_kernel<<<n_items, 256, 0, stream>>>(A);
}

// Round 3
// 4079.839 us; speedup vs baseline: 1.8168x; 1.8168x over previous
//
#include <hip/hip_runtime.h>
#include <hip/hip_bf16.h>
#include <math.h>
#include <type_traits>

#define NJ 22

// ---------------- LDS layout (floats) ----------------
// R1: 5632  (tok[22][64]@0 + qkv[22][192]@1408) / hid fp32 [22][256]
// R2: 5632  (h / hn fp32 (in place) / out_enc / embed)
// R3: 1408  (attn_out fp32 [22][64])
// S : 256   (x@0 (<=88), mean@96 (22), rstd@118 (22), delta@160 (88))
#define R2_OFF 5632
#define R3_OFF 11264
#define S_OFF  12672
#define LDS_FLOATS 12928
#define S_X 0
#define S_MEAN 96
#define S_RSTD 118
#define S_DELTA 160

struct Args {
    const float *q_t, *skelA, *skelB, *quat_mean, *quat_std;
    const float *qe_tok_W, *qe_tok_b, *qe_qkv_W, *qe_qkv_b, *qe_o_W, *qe_o_b;
    const float *qe_ln_g, *qe_ln_b, *qe_m1_W, *qe_m1_b, *qe_m2_W, *qe_m2_b;
    const float *se_tok_W, *se_tok_b, *se_qkv_W, *se_qkv_b, *se_o_W, *se_o_b;
    const float *se_ln_g, *se_ln_b, *se_m1_W, *se_m1_b, *se_m2_W, *se_m2_b;
    const float *emb_W, *emb_b, *del_W, *del_b;
    const float *P;   // precomputed pe @ emb_W + emb_b  [22][128]
    float *out;
};

// Row-group dispatch: rows 22 = 6/6/5/5 across waves (rg = t>>6, wave-uniform).
template <class F>
__device__ __forceinline__ void rgd(int rg, F &&f) {
    if (rg < 2) f(std::integral_constant<int, 6>());
    else        f(std::integral_constant<int, 5>());
}
__device__ __forceinline__ int rg_r0(int rg) {
    return (rg < 2) ? rg * 6 : 12 + (rg - 2) * 5;
}

// acc[i][r] += sum_k A[(r0+r)*LDA+k] * W[k*C + i*CS]
// A in LDS (wave-uniform rows -> broadcast b128 reads); W from global (coalesced
// across lanes since thread's W base = W_global + (t&63)).
template <int NR, int NC, int K, int LDA, int C, int CS>
__device__ __forceinline__ void gemm_rg(float (&acc)[NC][6], const float *__restrict__ W,
                                        const float *A, int r0) {
#pragma unroll 2
    for (int k = 0; k < K; k += 4) {
        float w[NC][4];
#pragma unroll
        for (int i = 0; i < NC; i++)
#pragma unroll
            for (int j = 0; j < 4; j++)
                w[i][j] = W[(k + j) * C + i * CS];
#pragma unroll
        for (int r = 0; r < NR; r++) {
            float4 a = *(const float4 *)(A + (r0 + r) * LDA + k);
#pragma unroll
            for (int i = 0; i < NC; i++)
                acc[i][r] = fmaf(a.x, w[i][0], fmaf(a.y, w[i][1],
                             fmaf(a.z, w[i][2], fmaf(a.w, w[i][3], acc[i][r]))));
        }
    }
}

// attention over QKV lds tile [22][192] (layout q|k|v each [heads][HD]); out O [22][64]
template <int H, int HD>
__device__ __forceinline__ void attention(const float *QKV, float *O, int t) {
    if (t < H * NJ) {
        int hh = t / NJ, r = t - hh * NJ;
        const float *qp = QKV + r * 192 + hh * HD;
        float q[HD];
#pragma unroll
        for (int d = 0; d < HD; d += 4) {
            float4 v4 = *(const float4 *)(qp + d);
            q[d] = v4.x; q[d + 1] = v4.y; q[d + 2] = v4.z; q[d + 3] = v4.w;
        }
        float s[NJ];
        float mx = -1e30f;
#pragma unroll
        for (int j = 0; j < NJ; j++) {
            const float *kp = QKV + j * 192 + 64 + hh * HD;
            float acc = 0.f;
#pragma unroll
            for (int d = 0; d < HD; d += 4) {
                float4 v4 = *(const float4 *)(kp + d);
                acc += q[d] * v4.x + q[d + 1] * v4.y + q[d + 2] * v4.z + q[d + 3] * v4.w;
            }
            s[j] = acc * 0.125f;            // scale = 64^-0.5 for both encoders
            mx = fmaxf(mx, s[j]);
        }
        float sum = 0.f;
#pragma unroll
        for (int j = 0; j < NJ; j++) { s[j] = expf(s[j] - mx); sum += s[j]; }
        float inv = 1.f / sum;
        float o[HD];
#pragma unroll
        for (int d = 0; d < HD; d++) o[d] = 0.f;
#pragma unroll
        for (int j = 0; j < NJ; j++) {
            float p = s[j] * inv;
            const float *vp = QKV + j * 192 + 128 + hh * HD;
#pragma unroll
            for (int d = 0; d < HD; d += 4) {
                float4 v4 = *(const float4 *)(vp + d);
                o[d] = fmaf(p, v4.x, o[d]);   o[d + 1] = fmaf(p, v4.y, o[d + 1]);
                o[d + 2] = fmaf(p, v4.z, o[d + 2]); o[d + 3] = fmaf(p, v4.w, o[d + 3]);
            }
        }
#pragma unroll
        for (int d = 0; d < HD; d++) O[r * 64 + hh * HD + d] = o[d];
    }
}

template <int CH>
__device__ __forceinline__ void ln_stats(const float *Hm, float *S, int t) {
    int wave = t >> 6, lane = t & 63;
    for (int r = wave; r < NJ; r += 4) {
        float s1 = 0.f, s2 = 0.f;
        for (int c = lane; c < CH; c += 64) {
            float v = Hm[r * CH + c];
            s1 += v; s2 = fmaf(v, v, s2);
        }
#pragma unroll
        for (int off = 32; off > 0; off >>= 1) {
            s1 += __shfl_down(s1, off);
            s2 += __shfl_down(s2, off);
        }
        if (lane == 0) {
            float m = s1 * (1.f / CH);
            float var = s2 * (1.f / CH) - m * m;
            S[S_MEAN + r] = m;
            S[S_RSTD + r] = rsqrtf(var + 1e-5f);
        }
    }
}

// One SkelEncoder pass; accumulates its emb_W slice into embacc[2][6].
__device__ __forceinline__ void se_encode(const Args &A, const float *X, int embBase,
                                          float *lds, float (&embacc)[2][6],
                                          int t, int rg, int r0, int cg) {
    float *R1 = lds, *R2 = lds + R2_OFF, *R3 = lds + R3_OFF, *S = lds + S_OFF;
    if (t < NJ * 3) S[S_X + t] = X[t];
    __syncthreads();
    rgd(rg, [&](auto NRC) {              // tok: C=64, K=3
        constexpr int NR = NRC.value;
        float acc[6];
        float b = A.se_tok_b[cg];
#pragma unroll
        for (int r = 0; r < NR; r++) acc[r] = b;
#pragma unroll
        for (int k = 0; k < 3; k++) {
            float w = A.se_tok_W[k * 64 + cg];
#pragma unroll
            for (int r = 0; r < NR; r++) acc[r] = fmaf(S[S_X + (r0 + r) * 3 + k], w, acc[r]);
        }
#pragma unroll
        for (int r = 0; r < NR; r++) R1[(r0 + r) * 64 + cg] = acc[r];
    });
    __syncthreads();
    rgd(rg, [&](auto NRC) {              // qkv: C=192, K=64, NC=3
        constexpr int NR = NRC.value;
        float acc[3][6];
#pragma unroll
        for (int i = 0; i < 3; i++) { float b = A.se_qkv_b[cg + i * 64];
#pragma unroll
            for (int r = 0; r < NR; r++) acc[i][r] = b; }
        gemm_rg<NR, 3, 64, 64, 192, 64>(acc, A.se_qkv_W + cg, R1, r0);
#pragma unroll
        for (int i = 0; i < 3; i++)
#pragma unroll
            for (int r = 0; r < NR; r++) R1[1408 + (r0 + r) * 192 + cg + i * 64] = acc[i][r];
    });
    __syncthreads();
    attention<2, 32>(R1 + 1408, R3, t);
    __syncthreads();
    float res2[2][6];
    rgd(rg, [&](auto NRC) {              // h = attn_out @ o_W: C=128, K=64, NC=2
        constexpr int NR = NRC.value;
#pragma unroll
        for (int i = 0; i < 2; i++) { float b = A.se_o_b[cg + i * 64];
#pragma unroll
            for (int r = 0; r < NR; r++) res2[i][r] = b; }
        gemm_rg<NR, 2, 64, 64, 128, 64>(res2, A.se_o_W + cg, R3, r0);
#pragma unroll
        for (int i = 0; i < 2; i++)
#pragma unroll
            for (int r = 0; r < NR; r++) R2[(r0 + r) * 128 + cg + i * 64] = res2[i][r];
    });
    __syncthreads();
    ln_stats<128>(R2, S, t);
    __syncthreads();
    rgd(rg, [&](auto NRC) {              // hn overwrites h in R2; res2 keeps h
        constexpr int NR = NRC.value;
#pragma unroll
        for (int i = 0; i < 2; i++) {
            int c = cg + i * 64;
            float g = A.se_ln_g[c], bb = A.se_ln_b[c];
#pragma unroll
            for (int r = 0; r < NR; r++)
                R2[(r0 + r) * 128 + c] = (res2[i][r] - S[S_MEAN + r0 + r]) * S[S_RSTD + r0 + r] * g + bb;
        }
    });
    __syncthreads();
    rgd(rg, [&](auto NRC) {              // mlp1: C=256, K=128, NC=4
        constexpr int NR = NRC.value;
        float acc[4][6];
#pragma unroll
        for (int i = 0; i < 4; i++) { float b = A.se_m1_b[cg + i * 64];
#pragma unroll
            for (int r = 0; r < NR; r++) acc[i][r] = b; }
        gemm_rg<NR, 4, 128, 128, 256, 64>(acc, A.se_m1_W + cg, R2, r0);
#pragma unroll
        for (int i = 0; i < 4; i++)
#pragma unroll
            for (int r = 0; r < NR; r++)
                R1[(r0 + r) * 256 + cg + i * 64] = fmaxf(acc[i][r], 0.f);
    });
    __syncthreads();
    rgd(rg, [&](auto NRC) {              // mlp2 + residual: C=128, K=256, NC=2
        constexpr int NR = NRC.value;
        gemm_rg<NR, 2, 256, 256, 128, 64>(res2, A.se_m2_W + cg, R1, r0);
#pragma unroll
        for (int i = 0; i < 2; i++) {
            float b2 = A.se_m2_b[cg + i * 64];
#pragma unroll
            for (int r = 0; r < NR; r++)
                R2[(r0 + r) * 128 + cg + i * 64] = res2[i][r] + b2;   // out_enc (hn reads done)
        }
    });
    __syncthreads();
    rgd(rg, [&](auto NRC) {              // embacc += out_enc @ emb_W[slice]: C=128, K=128, NC=2
        constexpr int NR = NRC.value;
        gemm_rg<NR, 2, 128, 128, 128, 64>(embacc, A.emb_W + embBase * 128 + cg, R2, r0);
    });
}

__global__ __launch_bounds__(256, 3) void fused_kernel(Args A) {
    __shared__ __align__(16) float lds[LDS_FLOATS];
    const int item = blockIdx.x;
    const int t = threadIdx.x;
    const int rg = t >> 6;              // wave id == row group
    const int r0 = rg_r0(rg);
    const int cg = t & 63;
    float *R1 = lds, *R2 = lds + R2_OFF, *R3 = lds + R3_OFF, *S = lds + S_OFF;

    float embacc[2][6] = {};            // cols cg+{0,64}, rows r0..r0+NR-1

    // ================= QuatEncoder =================
    if (t < NJ * 4) S[S_X + t] = A.q_t[item * NJ * 4 + t];
    __syncthreads();
    rgd(rg, [&](auto NRC) {              // tok: C=64, K=4
        constexpr int NR = NRC.value;
        float acc[6];
        float b = A.qe_tok_b[cg];
#pragma unroll
        for (int r = 0; r < NR; r++) acc[r] = b;
#pragma unroll
        for (int k = 0; k < 4; k++) {
            float w = A.qe_tok_W[k * 64 + cg];
#pragma unroll
            for (int r = 0; r < NR; r++) acc[r] = fmaf(S[S_X + (r0 + r) * 4 + k], w, acc[r]);
        }
#pragma unroll
        for (int r = 0; r < NR; r++) R1[(r0 + r) * 64 + cg] = acc[r];
    });
    __syncthreads();
    rgd(rg, [&](auto NRC) {              // qkv: C=192, K=64, NC=3
        constexpr int NR = NRC.value;
        float acc[3][6];
#pragma unroll
        for (int i = 0; i < 3; i++) { float b = A.qe_qkv_b[cg + i * 64];
#pragma unroll
            for (int r = 0; r < NR; r++) acc[i][r] = b; }
        gemm_rg<NR, 3, 64, 64, 192, 64>(acc, A.qe_qkv_W + cg, R1, r0);
#pragma unroll
        for (int i = 0; i < 3; i++)
#pragma unroll
            for (int r = 0; r < NR; r++) R1[1408 + (r0 + r) * 192 + cg + i * 64] = acc[i][r];
    });
    __syncthreads();
    attention<4, 16>(R1 + 1408, R3, t);
    __syncthreads();
    float res4[4][6];
    rgd(rg, [&](auto NRC) {              // h = attn_out @ o_W: C=256, K=64, NC=4
        constexpr int NR = NRC.value;
#pragma unroll
        for (int i = 0; i < 4; i++) { float b = A.qe_o_b[cg + i * 64];
#pragma unroll
            for (int r = 0; r < NR; r++) res4[i][r] = b; }
        gemm_rg<NR, 4, 64, 64, 256, 64>(res4, A.qe_o_W + cg, R3, r0);
#pragma unroll
        for (int i = 0; i < 4; i++)
#pragma unroll
            for (int r = 0; r < NR; r++) R2[(r0 + r) * 256 + cg + i * 64] = res4[i][r];
    });
    __syncthreads();
    ln_stats<256>(R2, S, t);
    __syncthreads();
    rgd(rg, [&](auto NRC) {              // hn overwrites h in R2; res4 keeps h
        constexpr int NR = NRC.value;
#pragma unroll
        for (int i = 0; i < 4; i++) {
            int c = cg + i * 64;
            float g = A.qe_ln_g[c], bb = A.qe_ln_b[c];
#pragma unroll
            for (int r = 0; r < NR; r++)
                R2[(r0 + r) * 256 + c] = (res4[i][r] - S[S_MEAN + r0 + r]) * S[S_RSTD + r0 + r] * g + bb;
        }
    });
    __syncthreads();
#pragma unroll 1
    for (int p = 0; p < 2; p++) {       // mlp over hid halves of 512
        rgd(rg, [&](auto NRC) {          // mlp1 half: C=256(of 512), K=256, NC=4
            constexpr int NR = NRC.value;
            float acc[4][6];
#pragma unroll
            for (int i = 0; i < 4; i++) { float b = A.qe_m1_b[p * 256 + cg + i * 64];
#pragma unroll
                for (int r = 0; r < NR; r++) acc[i][r] = b; }
            gemm_rg<NR, 4, 256, 256, 512, 64>(acc, A.qe_m1_W + p * 256 + cg, R2, r0);
#pragma unroll
            for (int i = 0; i < 4; i++)
#pragma unroll
                for (int r = 0; r < NR; r++)
                    R1[(r0 + r) * 256 + cg + i * 64] = fmaxf(acc[i][r], 0.f);
        });
        __syncthreads();
        rgd(rg, [&](auto NRC) {          // mlp2 half accum into res4: C=256, K=256, NC=4
            constexpr int NR = NRC.value;
            gemm_rg<NR, 4, 256, 256, 256, 64>(res4, A.qe_m2_W + p * 65536 + cg, R1, r0);
        });
        __syncthreads();
    }
    rgd(rg, [&](auto NRC) {              // out_enc = res4 + b2  (hn reads done after p-loop syncs)
        constexpr int NR = NRC.value;
#pragma unroll
        for (int i = 0; i < 4; i++) {
            float b2 = A.qe_m2_b[cg + i * 64];
#pragma unroll
            for (int r = 0; r < NR; r++) R2[(r0 + r) * 256 + cg + i * 64] = res4[i][r] + b2;
        }
    });
    __syncthreads();
    rgd(rg, [&](auto NRC) {              // embacc += qe_out @ emb_W[0:256]: C=128, K=256, NC=2
        constexpr int NR = NRC.value;
        gemm_rg<NR, 2, 256, 256, 128, 64>(embacc, A.emb_W + cg, R2, r0);
    });
    __syncthreads();

    // ================= SkelEncoders (shared weights) =================
    se_encode(A, A.skelA + item * NJ * 3, 256, lds, embacc, t, rg, r0, cg);
    __syncthreads();
    se_encode(A, A.skelB + item * NJ * 3, 384, lds, embacc, t, rg, r0, cg);

    // ================= Head =================
    __syncthreads();                     // emb-fold reads of R2 done
    rgd(rg, [&](auto NRC) {
        constexpr int NR = NRC.value;
#pragma unroll
        for (int i = 0; i < 2; i++) {
            int c = cg + i * 64;
#pragma unroll
            for (int r = 0; r < NR; r++) {
                float e = fmaf(22.627416997969522f, embacc[i][r], A.P[(r0 + r) * 128 + c]);
                R2[(r0 + r) * 128 + c] = fmaxf(e, 0.f);
            }
        }
    });
    __syncthreads();
    if (t < NJ * 4) {                   // delta = embed @ del_W + del_b, scale/shift
        int r = t >> 2, d = t & 3;
        float acc = A.del_b[d];
        for (int c = 0; c < 128; c++)
            acc = fmaf(R2[r * 128 + c], A.del_W[c * 4 + d], acc);
        acc = fmaf(acc, A.quat_std[t], A.quat_mean[t]);
        S[S_DELTA + t] = acc;
    }
    __syncthreads();
    if (t < NJ * 4) {                   // normalize quaternion
        int r = t >> 2;
        float x0 = S[S_DELTA + r * 4 + 0], x1 = S[S_DELTA + r * 4 + 1];
        float x2 = S[S_DELTA + r * 4 + 2], x3 = S[S_DELTA + r * 4 + 3];
        float inv = 1.f / sqrtf(x0 * x0 + x1 * x1 + x2 * x2 + x3 * x3);
        A.out[item * NJ * 4 + t] = S[S_DELTA + t] * inv;
    }
}

// Setup: P[r][c] = (pe @ emb_W)[r][c] + emb_b[c]   (pos = cat*sqrt(512) + pe)
// Precise math: runs once over 22*128 outputs, cost negligible.
__global__ void pe_emb_kernel(const float *__restrict__ emb_W,
                              const float *__restrict__ emb_b, float *P) {
    int r = blockIdx.x;        // 0..21
    int c = threadIdx.x;       // 0..127
    float acc = emb_b[c];
    const float k = -2.f * logf(10000.f) / 512.f;
    for (int i = 0; i < 256; i++) {
        float ang = (float)r * expf((float)i * k);
        acc = fmaf(sinf(ang), emb_W[(2 * i) * 128 + c], acc);
        acc = fmaf(cosf(ang), emb_W[(2 * i + 1) * 128 + c], acc);
    }
    P[r * 128 + c] = acc;
}

extern "C" void kernel_launch(void *const *d_in, const int *in_sizes, int n_in,
                              void *d_out, int out_size, void *d_ws, size_t ws_size,
                              hipStream_t stream) {
    Args A;
    const float **p = (const float **)&A;
    for (int i = 0; i < 33; i++) p[i] = (const float *)d_in[i];
    float *P = (float *)d_ws;
    A.P = P;
    A.out = (float *)d_out;
    int n_items = in_sizes[0] / (NJ * 4);

    pe_emb_kernel<<<NJ, 128, 0, stream>>>(A.emb_W, A.emb_b, P);
    fused_kernel<<<n_items, 256, 0, stream>>>(A);
}

// Round 4
// 2152.871 us; speedup vs baseline: 3.4430x; 1.8951x over previous
//
#include <hip/hip_runtime.h>
#include <hip/hip_bf16.h>
#include <math.h>

#define NJ 22
#define MROWS 44          // 2 items x 22 joints per block
#define NRT 3             // 3 row-tiles of 16 (rows 0..47, 44 real)

typedef float f4 __attribute__((ext_vector_type(4)));
typedef _Float16 h8 __attribute__((ext_vector_type(8)));

// ---- d_ws layout ----
// float P[22*128]  (pe @ emb_W + emb_b)
// then fp16 weight planes (hi plane [N][K], then lo plane [N][K]) at offsets:
#define WOFF_QE_QKV 0        // K=64  N=192
#define WOFF_QE_O   24576    // K=64  N=256
#define WOFF_QE_M1  57344    // K=256 N=512
#define WOFF_QE_M2  319488   // K=512 N=256
#define WOFF_SE_QKV 581632   // K=64  N=192
#define WOFF_SE_O   606208   // K=64  N=128
#define WOFF_SE_M1  622592   // K=128 N=256
#define WOFF_SE_M2  688128   // K=256 N=128
#define WOFF_EMB    753664   // K=512 N=128

struct Smem {
    _Float16 XH[MROWS * 256];   // activation hi plane (swizzled [r][256])
    _Float16 XL[MROWS * 256];   // activation lo plane
    _Float16 HH[MROWS * 128];   // mlp-hidden tile hi  (also KF/VF fp32, also head E fp32)
    _Float16 HL[MROWS * 128];   // mlp-hidden tile lo
    float LNp[48 * 4], LNq[48 * 4];
    float LNm[48], LNr[48];
    float Sx[MROWS * 4];
    float Sd[MROWS * 4];
    char tail[2048];            // pad: A-frag reads of rows 44..47 land in-bounds
};

struct EncW {
    const float *tokW, *tokB, *qkvB, *oB, *lnG, *lnB, *m1B, *m2B;
    const _Float16 *Wq, *Wo, *Wm1, *Wm2;
};

struct Args {
    const float *q_t, *skelA, *skelB, *quat_mean, *quat_std;
    const float *qe_tok_W, *qe_tok_b, *qe_qkv_b, *qe_o_b, *qe_ln_g, *qe_ln_b, *qe_m1_b, *qe_m2_b;
    const float *se_tok_W, *se_tok_b, *se_qkv_b, *se_o_b, *se_ln_g, *se_ln_b, *se_m1_b, *se_m2_b;
    const float *del_W, *del_b;
    const float *P;
    const _Float16 *W;
    float *out;
};

// XOR-chunk swizzle within a row: chunk = c>>3 (8 fp16 = 16B), chunk' = chunk ^ (r&7).
// Closed within any aligned 64-col group; makes A-frag ds_read_b128 conflict-light.
__device__ __forceinline__ int swz(int r, int c) {
    return (((c >> 3) ^ (r & 7)) << 3) | (c & 7);
}

__device__ __forceinline__ void wr_hilo(_Float16 *PH, _Float16 *PL, int a, float v) {
    _Float16 h = (_Float16)v;
    PH[a] = h;
    PL[a] = (_Float16)(v - (float)h);
}

// acc[i][rt] += A[rt*16.., kA] * B[n=(w+4i)*16.., koff+kA]  with dual-plane 3-MFMA
// A from LDS planes (row stride LDA, swizzled); B from global WT planes ([N][wK] fp16).
template<int NI, int KSTEPS, int LDA>
__device__ __forceinline__ void mfma_gemm(f4 (&acc)[NI][NRT],
        const _Float16 *AH, const _Float16 *AL,
        const _Float16 *BH, const _Float16 *BL,
        int wK, int koff, int w, int l) {
    const int m = l & 15, q = l >> 4;
#pragma unroll
    for (int s = 0; s < KSTEPS; s++) {
        const int ka = s * 32 + q * 8;       // this lane's A/B k-range base
        h8 a[NRT][2];
#pragma unroll
        for (int rt = 0; rt < NRT; rt++) {
            int r = rt * 16 + m;
            int off = r * LDA + ((((ka >> 3) ^ (r & 7))) << 3);
            a[rt][0] = *(const h8 *)(AH + off);
            a[rt][1] = *(const h8 *)(AL + off);
        }
#pragma unroll
        for (int i = 0; i < NI; i++) {
            int n = (w + 4 * i) * 16 + m;
            int boff = n * wK + koff + ka;
            h8 bh = *(const h8 *)(BH + boff);
            h8 bl = *(const h8 *)(BL + boff);
#pragma unroll
            for (int rt = 0; rt < NRT; rt++) {
                acc[i][rt] = __builtin_amdgcn_mfma_f32_16x16x32_f16(a[rt][0], bh, acc[i][rt], 0, 0, 0);
                acc[i][rt] = __builtin_amdgcn_mfma_f32_16x16x32_f16(a[rt][1], bh, acc[i][rt], 0, 0, 0);
                acc[i][rt] = __builtin_amdgcn_mfma_f32_16x16x32_f16(a[rt][0], bl, acc[i][rt], 0, 0, 0);
            }
        }
    }
}

// attention: Q from X hi/lo (cols 64+hh*HD..), K/V fp32 from KF/VF; AO -> X cols 0:64
template<int NH, int HD>
__device__ __forceinline__ void attention(Smem &sm, int t) {
    if (t < NH * MROWS) {
        int hh = t / MROWS;
        int rr = t - hh * MROWS;
        int jb = (rr >= NJ) ? NJ : 0;
        const float *KF = (const float *)sm.HH;        // [44][64]
        const float *VF = KF + MROWS * 64;             // [44][64]
        float qv[HD];
#pragma unroll
        for (int d = 0; d < HD; d++) {
            int a = rr * 256 + swz(rr, 64 + hh * HD + d);
            qv[d] = (float)sm.XH[a] + (float)sm.XL[a];
        }
        float s[NJ];
        float mx = -1e30f;
#pragma unroll
        for (int j = 0; j < NJ; j++) {
            const float *kp = KF + (jb + j) * 64 + hh * HD;
            float acc = 0.f;
#pragma unroll
            for (int d = 0; d < HD; d += 4) {
                float4 v = *(const float4 *)(kp + d);
                acc += qv[d] * v.x + qv[d + 1] * v.y + qv[d + 2] * v.z + qv[d + 3] * v.w;
            }
            s[j] = acc * 0.125f;        // scale = 64^-0.5 for both encoders
            mx = fmaxf(mx, s[j]);
        }
        float sum = 0.f;
#pragma unroll
        for (int j = 0; j < NJ; j++) { s[j] = expf(s[j] - mx); sum += s[j]; }
        float inv = 1.f / sum;
        float o[HD];
#pragma unroll
        for (int d = 0; d < HD; d++) o[d] = 0.f;
#pragma unroll
        for (int j = 0; j < NJ; j++) {
            float p = s[j] * inv;
            const float *vp = VF + (jb + j) * 64 + hh * HD;
#pragma unroll
            for (int d = 0; d < HD; d += 4) {
                float4 v = *(const float4 *)(vp + d);
                o[d] = fmaf(p, v.x, o[d]);       o[d + 1] = fmaf(p, v.y, o[d + 1]);
                o[d + 2] = fmaf(p, v.z, o[d + 2]); o[d + 3] = fmaf(p, v.w, o[d + 3]);
            }
        }
#pragma unroll
        for (int d = 0; d < HD; d++)
            wr_hilo(sm.XH, sm.XL, rr * 256 + swz(rr, hh * HD + d), o[d]);
    }
}

template<int D, int NH, int TK>
__device__ __forceinline__ void encode(Smem &sm, const float *__restrict__ xg,
        const EncW &ew, const _Float16 *Wemb, int embKoff,
        f4 (&emb)[2][NRT], int t, int w, int l) {
    constexpr int NI = D / 64;
    constexpr int HID = 2 * D;
    constexpr int HD = 64 / NH;
    const int m = l & 15, q = l >> 4;

    if (t < MROWS * TK) sm.Sx[t] = xg[t];
    __syncthreads();                       // also guards prior fold's X reads
    // ---- tok (VALU): T[44][64] -> X cols 0:64
    {
        float b = ew.tokB[l];
#pragma unroll
        for (int i = 0; i < 11; i++) {
            int r = w + 4 * i;
            float acc = b;
#pragma unroll
            for (int k = 0; k < TK; k++)
                acc = fmaf(sm.Sx[r * TK + k], ew.tokW[k * 64 + l], acc);
            wr_hilo(sm.XH, sm.XL, r * 256 + swz(r, l), acc);
        }
    }
    __syncthreads();
    // ---- qkv GEMM: [44][192] -> X cols 64:256 (hi/lo); k,v also fp32 -> KF/VF
    {
        f4 acc[3][NRT];
#pragma unroll
        for (int i = 0; i < 3; i++)
#pragma unroll
            for (int rt = 0; rt < NRT; rt++) acc[i][rt] = (f4){0.f, 0.f, 0.f, 0.f};
        mfma_gemm<3, 2, 256>(acc, sm.XH, sm.XL, ew.Wq, ew.Wq + 192 * 64, 64, 0, w, l);
        float *KV = (float *)sm.HH;
#pragma unroll
        for (int i = 0; i < 3; i++) {
            int c = (w + 4 * i) * 16 + m;
            float b = ew.qkvB[c];
#pragma unroll
            for (int rt = 0; rt < NRT; rt++)
#pragma unroll
                for (int e = 0; e < 4; e++) {
                    int r = rt * 16 + q * 4 + e;
                    if (r < MROWS) {
                        float v = acc[i][rt][e] + b;
                        wr_hilo(sm.XH, sm.XL, r * 256 + swz(r, 64 + c), v);
                        if (c >= 128)      KV[MROWS * 64 + r * 64 + (c - 128)] = v;  // V
                        else if (c >= 64)  KV[r * 64 + (c - 64)] = v;                // K
                    }
                }
        }
    }
    __syncthreads();
    attention<NH, HD>(sm, t);
    __syncthreads();
    // ---- o GEMM: res = AO @ Wo + oB   (N=D), kept in regs (residual)
    f4 res[NI][NRT];
#pragma unroll
    for (int i = 0; i < NI; i++)
#pragma unroll
        for (int rt = 0; rt < NRT; rt++) res[i][rt] = (f4){0.f, 0.f, 0.f, 0.f};
    mfma_gemm<NI, 2, 256>(res, sm.XH, sm.XL, ew.Wo, ew.Wo + D * 64, 64, 0, w, l);
#pragma unroll
    for (int i = 0; i < NI; i++) {
        float b = ew.oB[(w + 4 * i) * 16 + m];
#pragma unroll
        for (int rt = 0; rt < NRT; rt++)
#pragma unroll
            for (int e = 0; e < 4; e++) res[i][rt][e] += b;
    }
    // ---- LN stats (cross-wave via LDS)
#pragma unroll
    for (int rt = 0; rt < NRT; rt++)
#pragma unroll
        for (int e = 0; e < 4; e++) {
            int r = rt * 16 + q * 4 + e;
            float s1 = 0.f, s2 = 0.f;
#pragma unroll
            for (int i = 0; i < NI; i++) {
                float v = res[i][rt][e];
                s1 += v; s2 = fmaf(v, v, s2);
            }
#pragma unroll
            for (int off = 8; off > 0; off >>= 1) {
                s1 += __shfl_xor(s1, off);
                s2 += __shfl_xor(s2, off);
            }
            if (m == 0) { sm.LNp[r * 4 + w] = s1; sm.LNq[r * 4 + w] = s2; }
        }
    __syncthreads();
    if (t < 48) {
        float s1 = sm.LNp[t * 4] + sm.LNp[t * 4 + 1] + sm.LNp[t * 4 + 2] + sm.LNp[t * 4 + 3];
        float s2 = sm.LNq[t * 4] + sm.LNq[t * 4 + 1] + sm.LNq[t * 4 + 2] + sm.LNq[t * 4 + 3];
        float mean = s1 * (1.f / D);
        float var = s2 * (1.f / D) - mean * mean;
        sm.LNm[t] = mean;
        sm.LNr[t] = rsqrtf(var + 1e-5f);
    }
    __syncthreads();
    // ---- hn -> X cols 0:D (overwrites AO/qkv regions; res keeps h)
#pragma unroll
    for (int i = 0; i < NI; i++) {
        int c = (w + 4 * i) * 16 + m;
        float g = ew.lnG[c], bb = ew.lnB[c];
#pragma unroll
        for (int rt = 0; rt < NRT; rt++)
#pragma unroll
            for (int e = 0; e < 4; e++) {
                int r = rt * 16 + q * 4 + e;
                if (r < MROWS) {
                    float v = (res[i][rt][e] - sm.LNm[r]) * sm.LNr[r] * g + bb;
                    wr_hilo(sm.XH, sm.XL, r * 256 + swz(r, c), v);
                }
            }
    }
    __syncthreads();
    // ---- MLP: col-blocked hid (128 wide) through H planes; m2 accumulates in regs
    f4 macc[NI][NRT];
#pragma unroll
    for (int i = 0; i < NI; i++)
#pragma unroll
        for (int rt = 0; rt < NRT; rt++) macc[i][rt] = (f4){0.f, 0.f, 0.f, 0.f};
#pragma unroll 1
    for (int cb = 0; cb < HID / 128; cb++) {
        f4 h1[2][NRT];
#pragma unroll
        for (int i = 0; i < 2; i++)
#pragma unroll
            for (int rt = 0; rt < NRT; rt++) h1[i][rt] = (f4){0.f, 0.f, 0.f, 0.f};
        mfma_gemm<2, D / 32, 256>(h1, sm.XH, sm.XL,
                                  ew.Wm1 + cb * 128 * D, ew.Wm1 + HID * D + cb * 128 * D, D, 0, w, l);
        __syncthreads();               // prev cb's m2 H-reads done
#pragma unroll
        for (int i = 0; i < 2; i++) {
            int c = (w + 4 * i) * 16 + m;
            float b = ew.m1B[cb * 128 + c];
#pragma unroll
            for (int rt = 0; rt < NRT; rt++)
#pragma unroll
                for (int e = 0; e < 4; e++) {
                    int r = rt * 16 + q * 4 + e;
                    if (r < MROWS)
                        wr_hilo(sm.HH, sm.HL, r * 128 + swz(r, c), fmaxf(h1[i][rt][e] + b, 0.f));
                }
        }
        __syncthreads();
        mfma_gemm<NI, 4, 128>(macc, sm.HH, sm.HL, ew.Wm2, ew.Wm2 + D * HID, HID, cb * 128, w, l);
    }
    __syncthreads();
    // ---- out_enc = h + mlp + b2 -> X cols 0:D
#pragma unroll
    for (int i = 0; i < NI; i++) {
        int c = (w + 4 * i) * 16 + m;
        float b = ew.m2B[c];
#pragma unroll
        for (int rt = 0; rt < NRT; rt++)
#pragma unroll
            for (int e = 0; e < 4; e++) {
                int r = rt * 16 + q * 4 + e;
                if (r < MROWS)
                    wr_hilo(sm.XH, sm.XL, r * 256 + swz(r, c), res[i][rt][e] + macc[i][rt][e] + b);
            }
    }
    __syncthreads();
    // ---- fold into head: emb += out_enc @ emb_W[koff:koff+D, :]
    mfma_gemm<2, D / 32, 256>(emb, sm.XH, sm.XL, Wemb, Wemb + 128 * 512, 512, embKoff, w, l);
}

__global__ __launch_bounds__(256, 2) void fused_kernel(Args A) {
    __shared__ __align__(16) Smem sm;
    const int t = threadIdx.x, w = t >> 6, l = t & 63;
    const int m = l & 15, q = l >> 4;
    const int blk = blockIdx.x;

    f4 emb[2][NRT];
#pragma unroll
    for (int i = 0; i < 2; i++)
#pragma unroll
        for (int rt = 0; rt < NRT; rt++) emb[i][rt] = (f4){0.f, 0.f, 0.f, 0.f};

    EncW qe = { A.qe_tok_W, A.qe_tok_b, A.qe_qkv_b, A.qe_o_b, A.qe_ln_g, A.qe_ln_b,
                A.qe_m1_b, A.qe_m2_b,
                A.W + WOFF_QE_QKV, A.W + WOFF_QE_O, A.W + WOFF_QE_M1, A.W + WOFF_QE_M2 };
    EncW se = { A.se_tok_W, A.se_tok_b, A.se_qkv_b, A.se_o_b, A.se_ln_g, A.se_ln_b,
                A.se_m1_b, A.se_m2_b,
                A.W + WOFF_SE_QKV, A.W + WOFF_SE_O, A.W + WOFF_SE_M1, A.W + WOFF_SE_M2 };
    const _Float16 *Wemb = A.W + WOFF_EMB;

    encode<256, 4, 4>(sm, A.q_t + blk * MROWS * 4, qe, Wemb, 0, emb, t, w, l);
    encode<128, 2, 3>(sm, A.skelA + blk * MROWS * 3, se, Wemb, 256, emb, t, w, l);
    encode<128, 2, 3>(sm, A.skelB + blk * MROWS * 3, se, Wemb, 384, emb, t, w, l);

    __syncthreads();                    // folds' X reads done; free H region for E
    // ---- head: embed = relu(sqrt(512)*emb + P) -> E fp32 [44][128]
    float *E = (float *)sm.HH;
#pragma unroll
    for (int i = 0; i < 2; i++) {
        int c = (w + 4 * i) * 16 + m;
#pragma unroll
        for (int rt = 0; rt < NRT; rt++)
#pragma unroll
            for (int e = 0; e < 4; e++) {
                int r = rt * 16 + q * 4 + e;
                if (r < MROWS) {
                    int j = (r >= NJ) ? r - NJ : r;
                    float v = fmaf(22.627416997969522f, emb[i][rt][e], A.P[j * 128 + c]);
                    E[r * 128 + c] = fmaxf(v, 0.f);
                }
            }
    }
    __syncthreads();
    if (t < MROWS * 4) {
        int r = t >> 2, d = t & 3;
        float acc = A.del_b[d];
        for (int c = 0; c < 128; c++)
            acc = fmaf(E[r * 128 + c], A.del_W[c * 4 + d], acc);
        int j = (r >= NJ) ? r - NJ : r;
        acc = fmaf(acc, A.quat_std[j * 4 + d], A.quat_mean[j * 4 + d]);
        sm.Sd[t] = acc;
    }
    __syncthreads();
    if (t < MROWS * 4) {
        int r = t >> 2;
        float x0 = sm.Sd[r * 4], x1 = sm.Sd[r * 4 + 1];
        float x2 = sm.Sd[r * 4 + 2], x3 = sm.Sd[r * 4 + 3];
        float inv = 1.f / sqrtf(x0 * x0 + x1 * x1 + x2 * x2 + x3 * x3);
        A.out[blk * MROWS * 4 + t] = sm.Sd[t] * inv;
    }
}

// ---- setup: split+transpose all GEMM weights into [N][K] fp16 hi/lo planes ----
struct WDesc { const float *W; int K; int N; int off; };
struct SplitArgs { WDesc d[9]; _Float16 *out; };

__global__ void split_kernel(SplitArgs a) {
    WDesc d = a.d[blockIdx.y];
    int e = blockIdx.x * 256 + threadIdx.x;
    int tot = d.K * d.N;
    if (e < tot) {
        int n = e / d.K, k = e - n * d.K;
        float v = d.W[k * d.N + n];
        _Float16 h = (_Float16)v;
        a.out[d.off + e] = h;
        a.out[d.off + tot + e] = (_Float16)(v - (float)h);
    }
}

// P[r][c] = (pe @ emb_W)[r][c] + emb_b[c]
__global__ void pe_emb_kernel(const float *__restrict__ emb_W,
                              const float *__restrict__ emb_b, float *P) {
    int r = blockIdx.x;        // 0..21
    int c = threadIdx.x;       // 0..127
    float acc = emb_b[c];
    const float k = -2.f * logf(10000.f) / 512.f;
    for (int i = 0; i < 256; i++) {
        float ang = (float)r * expf((float)i * k);
        acc = fmaf(sinf(ang), emb_W[(2 * i) * 128 + c], acc);
        acc = fmaf(cosf(ang), emb_W[(2 * i + 1) * 128 + c], acc);
    }
    P[r * 128 + c] = acc;
}

extern "C" void kernel_launch(void *const *d_in, const int *in_sizes, int n_in,
                              void *d_out, int out_size, void *d_ws, size_t ws_size,
                              hipStream_t stream) {
    const float **in = (const float **)d_in;
    float *P = (float *)d_ws;
    _Float16 *W = (_Float16 *)((float *)d_ws + 22 * 128);

    Args A;
    A.q_t = in[0]; A.skelA = in[1]; A.skelB = in[2]; A.quat_mean = in[3]; A.quat_std = in[4];
    A.qe_tok_W = in[5]; A.qe_tok_b = in[6]; A.qe_qkv_b = in[8]; A.qe_o_b = in[10];
    A.qe_ln_g = in[11]; A.qe_ln_b = in[12]; A.qe_m1_b = in[14]; A.qe_m2_b = in[16];
    A.se_tok_W = in[17]; A.se_tok_b = in[18]; A.se_qkv_b = in[20]; A.se_o_b = in[22];
    A.se_ln_g = in[23]; A.se_ln_b = in[24]; A.se_m1_b = in[26]; A.se_m2_b = in[28];
    A.del_W = in[31]; A.del_b = in[32];
    A.P = P; A.W = W; A.out = (float *)d_out;

    SplitArgs sa;
    sa.d[0] = { in[7],  64, 192, WOFF_QE_QKV };   // qe_qkv_W
    sa.d[1] = { in[9],  64, 256, WOFF_QE_O };     // qe_o_W
    sa.d[2] = { in[13], 256, 512, WOFF_QE_M1 };   // qe_m1_W
    sa.d[3] = { in[15], 512, 256, WOFF_QE_M2 };   // qe_m2_W
    sa.d[4] = { in[19], 64, 192, WOFF_SE_QKV };   // se_qkv_W
    sa.d[5] = { in[21], 64, 128, WOFF_SE_O };     // se_o_W
    sa.d[6] = { in[25], 128, 256, WOFF_SE_M1 };   // se_m1_W
    sa.d[7] = { in[27], 256, 128, WOFF_SE_M2 };   // se_m2_W
    sa.d[8] = { in[29], 512, 128, WOFF_EMB };     // emb_W
    sa.out = W;

    int n_items = in_sizes[0] / (NJ * 4);
    int blocks = n_items / 2;

    split_kernel<<<dim3(512, 9), 256, 0, stream>>>(sa);
    pe_emb_kernel<<<NJ, 128, 0, stream>>>(in[29], in[30], P);
    fused_kernel<<<blocks, 256, 0, stream>>>(A);
}

// Round 5
// 1567.003 us; speedup vs baseline: 4.7303x; 1.3739x over previous
//
#include <hip/hip_runtime.h>
#include <hip/hip_bf16.h>
#include <math.h>

#define NJ 22
#define MROWS 44          // 2 items x 22 joints per block
#define PROWS 48          // padded rows (3 row-tiles of 16)
#define NRT 3

typedef float f4 __attribute__((ext_vector_type(4)));
typedef _Float16 h8 __attribute__((ext_vector_type(8)));

// ---- d_ws layout ----
// float P[22*128]  (pe @ emb_W + emb_b)
// then fp16 weight planes (hi plane [N][K], then lo plane [N][K]) at offsets:
#define WOFF_QE_QKV 0        // K=64  N=192
#define WOFF_QE_O   24576    // K=64  N=256
#define WOFF_QE_M1  57344    // K=256 N=512
#define WOFF_QE_M2  319488   // K=512 N=256
#define WOFF_SE_QKV 581632   // K=64  N=192
#define WOFF_SE_O   606208   // K=64  N=128
#define WOFF_SE_M1  622592   // K=128 N=256
#define WOFF_SE_M2  688128   // K=256 N=128
#define WOFF_EMB    753664   // K=512 N=128

struct Smem {
    _Float16 XH[PROWS * 256];   // activation hi plane (swizzled [r][256])
    _Float16 XL[PROWS * 256];   // activation lo plane
    _Float16 HH[PROWS * 128];   // mlp-hidden hi | KF fp32 [48][64] | head E fp32 (lower half)
    _Float16 HL[PROWS * 128];   // mlp-hidden lo | VF fp32 [48][64]
    float LNp[PROWS * 4], LNq[PROWS * 4];
    float LNm[PROWS], LNr[PROWS];
    float Sx[MROWS * 4];
    float Sd[MROWS * 4];
};

struct EncW {
    const float *tokW, *tokB, *qkvB, *oB, *lnG, *lnB, *m1B, *m2B;
    const _Float16 *Wq, *Wo, *Wm1, *Wm2;
};

struct Args {
    const float *q_t, *skelA, *skelB, *quat_mean, *quat_std;
    const float *qe_tok_W, *qe_tok_b, *qe_qkv_b, *qe_o_b, *qe_ln_g, *qe_ln_b, *qe_m1_b, *qe_m2_b;
    const float *se_tok_W, *se_tok_b, *se_qkv_b, *se_o_b, *se_ln_g, *se_ln_b, *se_m1_b, *se_m2_b;
    const float *del_W, *del_b;
    const float *P;
    const _Float16 *W;
    float *out;
};

// XOR-chunk swizzle within a row: chunk = c>>3 (8 fp16 = 16B), chunk' = chunk ^ (r&7).
__device__ __forceinline__ int swz(int r, int c) {
    return (((c >> 3) ^ (r & 7)) << 3) | (c & 7);
}

__device__ __forceinline__ void wr_hilo(_Float16 *PH, _Float16 *PL, int a, float v) {
    _Float16 h = (_Float16)v;
    PH[a] = h;
    PL[a] = (_Float16)(v - (float)h);
}

// acc[i][rt] += A[rt*16.., kA] * B[n=(w+4i)*16.., koff+kA]  dual-plane 3-MFMA
template<int NI, int KSTEPS, int LDA>
__device__ __forceinline__ void mfma_gemm(f4 (&acc)[NI][NRT],
        const _Float16 *AH, const _Float16 *AL,
        const _Float16 *BH, const _Float16 *BL,
        int wK, int koff, int w, int l) {
    const int m = l & 15, q = l >> 4;
#pragma unroll
    for (int s = 0; s < KSTEPS; s++) {
        const int ka = s * 32 + q * 8;
        h8 a[NRT][2];
#pragma unroll
        for (int rt = 0; rt < NRT; rt++) {
            int r = rt * 16 + m;
            int off = r * LDA + ((((ka >> 3) ^ (r & 7))) << 3);
            a[rt][0] = *(const h8 *)(AH + off);
            a[rt][1] = *(const h8 *)(AL + off);
        }
#pragma unroll
        for (int i = 0; i < NI; i++) {
            int n = (w + 4 * i) * 16 + m;
            int boff = n * wK + koff + ka;
            h8 bh = *(const h8 *)(BH + boff);
            h8 bl = *(const h8 *)(BL + boff);
#pragma unroll
            for (int rt = 0; rt < NRT; rt++) {
                acc[i][rt] = __builtin_amdgcn_mfma_f32_16x16x32_f16(a[rt][0], bh, acc[i][rt], 0, 0, 0);
                acc[i][rt] = __builtin_amdgcn_mfma_f32_16x16x32_f16(a[rt][1], bh, acc[i][rt], 0, 0, 0);
                acc[i][rt] = __builtin_amdgcn_mfma_f32_16x16x32_f16(a[rt][0], bl, acc[i][rt], 0, 0, 0);
            }
        }
    }
}

// attention: unit = (head,row[,half]); each unit covers 16 head-dims.
// SE (HD=32): lane pairs (u^1) combine QK partial dots via shfl_xor.
template<int NH, int HD>
__device__ __forceinline__ void attention(Smem &sm, int t) {
    constexpr int SPL = HD / 16;
    if (t < NH * MROWS * SPL) {
        const int half = t & (SPL - 1);
        const int ur = t / SPL;
        const int hh = ur / MROWS;
        const int rr = ur - hh * MROWS;
        const int jb = (rr >= NJ) ? NJ : 0;
        const float *KF = (const float *)sm.HH;          // [48][64]
        const float *VF = KF + PROWS * 64;               // [48][64]
        const int c0 = 64 + hh * HD + half * 16;         // q/k col base in X
        float qv[16];
#pragma unroll
        for (int g = 0; g < 2; g++) {
            int a = rr * 256 + swz(rr, c0 + g * 8);
            h8 qh = *(const h8 *)(sm.XH + a);
            h8 ql = *(const h8 *)(sm.XL + a);
#pragma unroll
            for (int d = 0; d < 8; d++) qv[g * 8 + d] = (float)qh[d] + (float)ql[d];
        }
        float s[NJ];
        float mx = -1e30f;
#pragma unroll
        for (int j = 0; j < NJ; j++) {
            const float *kp = KF + (jb + j) * 64 + hh * HD + half * 16;
            float acc = 0.f;
#pragma unroll
            for (int d = 0; d < 16; d += 4) {
                float4 v = *(const float4 *)(kp + d);
                acc += qv[d] * v.x + qv[d + 1] * v.y + qv[d + 2] * v.z + qv[d + 3] * v.w;
            }
            if constexpr (SPL == 2) acc += __shfl_xor(acc, 1);
            s[j] = acc * 0.125f;        // scale = 64^-0.5 for both encoders
            mx = fmaxf(mx, s[j]);
        }
        float sum = 0.f;
#pragma unroll
        for (int j = 0; j < NJ; j++) { s[j] = expf(s[j] - mx); sum += s[j]; }
        float inv = 1.f / sum;
        float o[16];
#pragma unroll
        for (int d = 0; d < 16; d++) o[d] = 0.f;
#pragma unroll
        for (int j = 0; j < NJ; j++) {
            float p = s[j] * inv;
            const float *vp = VF + (jb + j) * 64 + hh * HD + half * 16;
#pragma unroll
            for (int d = 0; d < 16; d += 4) {
                float4 v = *(const float4 *)(vp + d);
                o[d] = fmaf(p, v.x, o[d]);       o[d + 1] = fmaf(p, v.y, o[d + 1]);
                o[d + 2] = fmaf(p, v.z, o[d + 2]); o[d + 3] = fmaf(p, v.w, o[d + 3]);
            }
        }
        const int cw = hh * HD + half * 16;              // AO col base
#pragma unroll
        for (int g = 0; g < 2; g++) {
            h8 oh, ol;
#pragma unroll
            for (int d = 0; d < 8; d++) {
                float v = o[g * 8 + d];
                _Float16 h = (_Float16)v;
                oh[d] = h;
                ol[d] = (_Float16)(v - (float)h);
            }
            int a = rr * 256 + swz(rr, cw + g * 8);
            *(h8 *)(sm.XH + a) = oh;
            *(h8 *)(sm.XL + a) = ol;
        }
    }
}

template<int D, int NH, int TK>
__device__ __forceinline__ void encode(Smem &sm, const float *__restrict__ xg,
        const EncW &ew, const _Float16 *Wemb, int embKoff,
        f4 (&emb)[2][NRT], int t, int w, int l) {
    constexpr int NI = D / 64;
    constexpr int HID = 2 * D;
    const int m = l & 15, q = l >> 4;

    if (t < MROWS * TK) sm.Sx[t] = xg[t];
    __syncthreads();                       // also guards prior fold's X reads
    // ---- tok (VALU): rows 0..43 -> X cols 0:64
    {
        float b = ew.tokB[l];
#pragma unroll
        for (int i = 0; i < 11; i++) {
            int r = w + 4 * i;
            float acc = b;
#pragma unroll
            for (int k = 0; k < TK; k++)
                acc = fmaf(sm.Sx[r * TK + k], ew.tokW[k * 64 + l], acc);
            wr_hilo(sm.XH, sm.XL, r * 256 + swz(r, l), acc);
        }
    }
    __syncthreads();
    // ---- qkv GEMM -> X cols 64:256 (hi/lo); k,v also fp32 -> KF/VF
    {
        f4 acc[3][NRT];
#pragma unroll
        for (int i = 0; i < 3; i++)
#pragma unroll
            for (int rt = 0; rt < NRT; rt++) acc[i][rt] = (f4){0.f, 0.f, 0.f, 0.f};
        mfma_gemm<3, 2, 256>(acc, sm.XH, sm.XL, ew.Wq, ew.Wq + 192 * 64, 64, 0, w, l);
        float *KV = (float *)sm.HH;
#pragma unroll
        for (int i = 0; i < 3; i++) {
            int c = (w + 4 * i) * 16 + m;
            float b = ew.qkvB[c];
#pragma unroll
            for (int rt = 0; rt < NRT; rt++)
#pragma unroll
                for (int e = 0; e < 4; e++) {
                    int r = rt * 16 + q * 4 + e;
                    float v = acc[i][rt][e] + b;
                    wr_hilo(sm.XH, sm.XL, r * 256 + swz(r, 64 + c), v);
                    if (c >= 128)      KV[PROWS * 64 + r * 64 + (c - 128)] = v;  // V
                    else if (c >= 64)  KV[r * 64 + (c - 64)] = v;                // K
                }
        }
    }
    __syncthreads();
    attention<NH, 64 / NH>(sm, t);
    __syncthreads();
    // ---- o GEMM: res = AO @ Wo + oB  (residual; also the MLP accumulator)
    f4 res[NI][NRT];
#pragma unroll
    for (int i = 0; i < NI; i++)
#pragma unroll
        for (int rt = 0; rt < NRT; rt++) res[i][rt] = (f4){0.f, 0.f, 0.f, 0.f};
    mfma_gemm<NI, 2, 256>(res, sm.XH, sm.XL, ew.Wo, ew.Wo + D * 64, 64, 0, w, l);
#pragma unroll
    for (int i = 0; i < NI; i++) {
        float b = ew.oB[(w + 4 * i) * 16 + m];
#pragma unroll
        for (int rt = 0; rt < NRT; rt++)
#pragma unroll
            for (int e = 0; e < 4; e++) res[i][rt][e] += b;
    }
    // ---- LN stats (cross-wave via LDS)
#pragma unroll
    for (int rt = 0; rt < NRT; rt++)
#pragma unroll
        for (int e = 0; e < 4; e++) {
            int r = rt * 16 + q * 4 + e;
            float s1 = 0.f, s2 = 0.f;
#pragma unroll
            for (int i = 0; i < NI; i++) {
                float v = res[i][rt][e];
                s1 += v; s2 = fmaf(v, v, s2);
            }
#pragma unroll
            for (int off = 8; off > 0; off >>= 1) {
                s1 += __shfl_xor(s1, off);
                s2 += __shfl_xor(s2, off);
            }
            if (m == 0) { sm.LNp[r * 4 + w] = s1; sm.LNq[r * 4 + w] = s2; }
        }
    __syncthreads();
    if (t < PROWS) {
        float s1 = sm.LNp[t * 4] + sm.LNp[t * 4 + 1] + sm.LNp[t * 4 + 2] + sm.LNp[t * 4 + 3];
        float s2 = sm.LNq[t * 4] + sm.LNq[t * 4 + 1] + sm.LNq[t * 4 + 2] + sm.LNq[t * 4 + 3];
        float mean = s1 * (1.f / D);
        float var = s2 * (1.f / D) - mean * mean;
        sm.LNm[t] = mean;
        sm.LNr[t] = rsqrtf(fmaxf(var, 0.f) + 1e-5f);
    }
    __syncthreads();
    // ---- hn -> X cols 0:D (res keeps h)
#pragma unroll
    for (int i = 0; i < NI; i++) {
        int c = (w + 4 * i) * 16 + m;
        float g = ew.lnG[c], bb = ew.lnB[c];
#pragma unroll
        for (int rt = 0; rt < NRT; rt++)
#pragma unroll
            for (int e = 0; e < 4; e++) {
                int r = rt * 16 + q * 4 + e;
                float v = (res[i][rt][e] - sm.LNm[r]) * sm.LNr[r] * g + bb;
                wr_hilo(sm.XH, sm.XL, r * 256 + swz(r, c), v);
            }
    }
    __syncthreads();
    // ---- MLP: hid in 128-col blocks through H planes; m2 accumulates into res
#pragma unroll 1
    for (int cb = 0; cb < HID / 128; cb++) {
        f4 h1[2][NRT];
#pragma unroll
        for (int i = 0; i < 2; i++)
#pragma unroll
            for (int rt = 0; rt < NRT; rt++) h1[i][rt] = (f4){0.f, 0.f, 0.f, 0.f};
        mfma_gemm<2, D / 32, 256>(h1, sm.XH, sm.XL,
                                  ew.Wm1 + cb * 128 * D, ew.Wm1 + HID * D + cb * 128 * D, D, 0, w, l);
        __syncthreads();               // prev cb's m2 H-reads done
#pragma unroll
        for (int i = 0; i < 2; i++) {
            int c = (w + 4 * i) * 16 + m;
            float b = ew.m1B[cb * 128 + c];
#pragma unroll
            for (int rt = 0; rt < NRT; rt++)
#pragma unroll
                for (int e = 0; e < 4; e++) {
                    int r = rt * 16 + q * 4 + e;
                    wr_hilo(sm.HH, sm.HL, r * 128 + swz(r, c), fmaxf(h1[i][rt][e] + b, 0.f));
                }
        }
        __syncthreads();
        mfma_gemm<NI, 4, 128>(res, sm.HH, sm.HL, ew.Wm2, ew.Wm2 + D * HID, HID, cb * 128, w, l);
    }
    __syncthreads();
    // ---- out_enc = res + b2 -> X cols 0:D
#pragma unroll
    for (int i = 0; i < NI; i++) {
        int c = (w + 4 * i) * 16 + m;
        float b = ew.m2B[c];
#pragma unroll
        for (int rt = 0; rt < NRT; rt++)
#pragma unroll
            for (int e = 0; e < 4; e++) {
                int r = rt * 16 + q * 4 + e;
                wr_hilo(sm.XH, sm.XL, r * 256 + swz(r, c), res[i][rt][e] + b);
            }
    }
    __syncthreads();
    // ---- fold into head: emb += out_enc @ emb_W[koff:koff+D, :]
    mfma_gemm<2, D / 32, 256>(emb, sm.XH, sm.XL, Wemb, Wemb + 128 * 512, 512, embKoff, w, l);
}

__global__ __launch_bounds__(256, 2) void fused_kernel(Args A) {
    __shared__ __align__(16) Smem sm;
    const int t = threadIdx.x, w = t >> 6, l = t & 63;
    const int m = l & 15, q = l >> 4;
    const int blk = blockIdx.x;

    // zero pad rows 44..47 of X planes (only rows never rewritten before first read)
    for (int i = t; i < 4 * 256; i += 256) {
        int r = MROWS + (i >> 8), c = i & 255;
        sm.XH[r * 256 + c] = (_Float16)0.f;
        sm.XL[r * 256 + c] = (_Float16)0.f;
    }

    f4 emb[2][NRT];
#pragma unroll
    for (int i = 0; i < 2; i++)
#pragma unroll
        for (int rt = 0; rt < NRT; rt++) emb[i][rt] = (f4){0.f, 0.f, 0.f, 0.f};

    EncW qe = { A.qe_tok_W, A.qe_tok_b, A.qe_qkv_b, A.qe_o_b, A.qe_ln_g, A.qe_ln_b,
                A.qe_m1_b, A.qe_m2_b,
                A.W + WOFF_QE_QKV, A.W + WOFF_QE_O, A.W + WOFF_QE_M1, A.W + WOFF_QE_M2 };
    EncW se = { A.se_tok_W, A.se_tok_b, A.se_qkv_b, A.se_o_b, A.se_ln_g, A.se_ln_b,
                A.se_m1_b, A.se_m2_b,
                A.W + WOFF_SE_QKV, A.W + WOFF_SE_O, A.W + WOFF_SE_M1, A.W + WOFF_SE_M2 };
    const _Float16 *Wemb = A.W + WOFF_EMB;

    encode<256, 4, 4>(sm, A.q_t + blk * MROWS * 4, qe, Wemb, 0, emb, t, w, l);
    encode<128, 2, 3>(sm, A.skelA + blk * MROWS * 3, se, Wemb, 256, emb, t, w, l);
    encode<128, 2, 3>(sm, A.skelB + blk * MROWS * 3, se, Wemb, 384, emb, t, w, l);

    __syncthreads();                    // folds' X reads done; free H region for E
    // ---- head: embed = relu(sqrt(512)*emb + P) -> E fp32 [48][128]
    float *E = (float *)sm.HH;
#pragma unroll
    for (int i = 0; i < 2; i++) {
        int c = (w + 4 * i) * 16 + m;
#pragma unroll
        for (int rt = 0; rt < NRT; rt++)
#pragma unroll
            for (int e = 0; e < 4; e++) {
                int r = rt * 16 + q * 4 + e;
                int j = (r >= NJ) ? r - NJ : r;
                j = (j >= NJ) ? 0 : j;          // pad rows: any valid index
                float v = fmaf(22.627416997969522f, emb[i][rt][e], A.P[j * 128 + c]);
                E[r * 128 + c] = fmaxf(v, 0.f);
            }
    }
    __syncthreads();
    if (t < MROWS * 4) {
        int r = t >> 2, d = t & 3;
        float acc = A.del_b[d];
        for (int c = 0; c < 128; c++)
            acc = fmaf(E[r * 128 + c], A.del_W[c * 4 + d], acc);
        int j = (r >= NJ) ? r - NJ : r;
        acc = fmaf(acc, A.quat_std[j * 4 + d], A.quat_mean[j * 4 + d]);
        sm.Sd[t] = acc;
    }
    __syncthreads();
    if (t < MROWS * 4) {
        int r = t >> 2;
        float x0 = sm.Sd[r * 4], x1 = sm.Sd[r * 4 + 1];
        float x2 = sm.Sd[r * 4 + 2], x3 = sm.Sd[r * 4 + 3];
        float inv = 1.f / sqrtf(x0 * x0 + x1 * x1 + x2 * x2 + x3 * x3);
        A.out[blk * MROWS * 4 + t] = sm.Sd[t] * inv;
    }
}

// ---- setup: split+transpose all GEMM weights into [N][K] fp16 hi/lo planes ----
struct WDesc { const float *W; int K; int N; int off; };
struct SplitArgs { WDesc d[9]; _Float16 *out; };

__global__ void split_kernel(SplitArgs a) {
    WDesc d = a.d[blockIdx.y];
    int e = blockIdx.x * 256 + threadIdx.x;
    int tot = d.K * d.N;
    if (e < tot) {
        int n = e / d.K, k = e - n * d.K;
        float v = d.W[k * d.N + n];
        _Float16 h = (_Float16)v;
        a.out[d.off + e] = h;
        a.out[d.off + tot + e] = (_Float16)(v - (float)h);
    }
}

// P[r][c] = (pe @ emb_W)[r][c] + emb_b[c]
__global__ void pe_emb_kernel(const float *__restrict__ emb_W,
                              const float *__restrict__ emb_b, float *P) {
    int r = blockIdx.x;        // 0..21
    int c = threadIdx.x;       // 0..127
    float acc = emb_b[c];
    const float k = -2.f * logf(10000.f) / 512.f;
    for (int i = 0; i < 256; i++) {
        float ang = (float)r * expf((float)i * k);
        acc = fmaf(sinf(ang), emb_W[(2 * i) * 128 + c], acc);
        acc = fmaf(cosf(ang), emb_W[(2 * i + 1) * 128 + c], acc);
    }
    P[r * 128 + c] = acc;
}

extern "C" void kernel_launch(void *const *d_in, const int *in_sizes, int n_in,
                              void *d_out, int out_size, void *d_ws, size_t ws_size,
                              hipStream_t stream) {
    const float **in = (const float **)d_in;
    float *P = (float *)d_ws;
    _Float16 *W = (_Float16 *)((float *)d_ws + 22 * 128);

    Args A;
    A.q_t = in[0]; A.skelA = in[1]; A.skelB = in[2]; A.quat_mean = in[3]; A.quat_std = in[4];
    A.qe_tok_W = in[5]; A.qe_tok_b = in[6]; A.qe_qkv_b = in[8]; A.qe_o_b = in[10];
    A.qe_ln_g = in[11]; A.qe_ln_b = in[12]; A.qe_m1_b = in[14]; A.qe_m2_b = in[16];
    A.se_tok_W = in[17]; A.se_tok_b = in[18]; A.se_qkv_b = in[20]; A.se_o_b = in[22];
    A.se_ln_g = in[23]; A.se_ln_b = in[24]; A.se_m1_b = in[26]; A.se_m2_b = in[28];
    A.del_W = in[31]; A.del_b = in[32];
    A.P = P; A.W = W; A.out = (float *)d_out;

    SplitArgs sa;
    sa.d[0] = { in[7],  64, 192, WOFF_QE_QKV };   // qe_qkv_W
    sa.d[1] = { in[9],  64, 256, WOFF_QE_O };     // qe_o_W
    sa.d[2] = { in[13], 256, 512, WOFF_QE_M1 };   // qe_m1_W
    sa.d[3] = { in[15], 512, 256, WOFF_QE_M2 };   // qe_m2_W
    sa.d[4] = { in[19], 64, 192, WOFF_SE_QKV };   // se_qkv_W
    sa.d[5] = { in[21], 64, 128, WOFF_SE_O };     // se_o_W
    sa.d[6] = { in[25], 128, 256, WOFF_SE_M1 };   // se_m1_W
    sa.d[7] = { in[27], 256, 128, WOFF_SE_M2 };   // se_m2_W
    sa.d[8] = { in[29], 512, 128, WOFF_EMB };     // emb_W
    sa.out = W;

    int n_items = in_sizes[0] / (NJ * 4);
    int blocks = n_items / 2;

    split_kernel<<<dim3(512, 9), 256, 0, stream>>>(sa);
    pe_emb_kernel<<<NJ, 128, 0, stream>>>(in[29], in[30], P);
    fused_kernel<<<blocks, 256, 0, stream>>>(A);
}